// Round 5
// baseline (107.671 us; speedup 1.0000x reference)
//
#include <hip/hip_runtime.h>

#define TEMP 0.7f
#define LOG2E 1.4426950408889634f
#define LN2 0.6931471805599453f
#define NPIX 8192
#define CDIM 128
// sqrt(LOG2E / TEMP): fold exp2-conversion + temperature into bf16 operands
#define FSCALE 1.4356161f
// exp(1/TEMP) = exp(diag) since features are L2-normalized (|F|^2 == 1)
#define EXPDIAG 4.1727352f

typedef __bf16 v8bf __attribute__((ext_vector_type(8)));
typedef float f32x4 __attribute__((ext_vector_type(4)));

// workspace layout (float offsets)
#define OFF_G      0            // 4*128 floats
#define OFF_COUNTS 512          // int[4]
#define OFF_ACC    516          // 1 float
#define OFF_ZERON  520          // zero the first OFF_ZERON floats
#define OFF_PART   1024         // 32 * 8192 floats (per-colchunk rowsum partials)
#define OFF_SWF    (1024 + 32 * NPIX)   // NPIX*CDIM bf16

__global__ __launch_bounds__(256) void k0_zero(float* __restrict__ w) {
    const int i = blockIdx.x * 256 + threadIdx.x;
    if (i < OFF_ZERON) w[i] = 0.0f;
}

// Transpose-build: coalesced feats reads -> LDS tile (128c x 64p, pad 65),
// then emit swizzled bf16 MFMA fragments, class sums G, counts.
__global__ __launch_bounds__(256) void k1_build(
    const float* __restrict__ feats, const int* __restrict__ labels,
    v8bf* __restrict__ swf, float* __restrict__ G, int* __restrict__ counts)
{
    __shared__ float lds[128][65];
    __shared__ int lab_l[64];
    __shared__ float cs[2][4][128];

    const int t = threadIdx.x;
    const int lane = t & 63, cg = t >> 6;
    const int bp = blockIdx.x >> 4;   // b' = row-block in concat order, 0..7
    const int pc = blockIdx.x & 15;   // 64-pixel chunk
    const int b = bp & 3, v = bp >> 2;
    const int bv = b * 2 + v;         // index into feats/labels batch dim
    const int p0 = pc * 64;
    const int nbase = bp * 1024 + p0;

    // coalesced load: each wave reads 256B rows of a fixed channel
    const float* src = feats + (size_t)bv * CDIM * 1024 + p0;
#pragma unroll
    for (int i = 0; i < 32; i++) {
        const int c = cg * 32 + i;
        lds[c][lane] = src[c * 1024 + lane];
    }
    // labels + counts (wave 0 only; t == lane there)
    if (t < 64) {
        const int lab = labels[bv * 1024 + p0 + t];
        lab_l[t] = lab;
#pragma unroll
        for (int k = 0; k < 4; k++) {
            unsigned long long m = __ballot(lab == k);
            if (t == 0) atomicAdd(&counts[k], (int)__popcll(m));
        }
    }
    __syncthreads();

    // per-class partial sums over this block's 64 pixels
    {
        const int cw = t & 127, h = t >> 7;
        float s0 = 0.f, s1 = 0.f, s2 = 0.f, s3 = 0.f;
#pragma unroll
        for (int i = 0; i < 32; i++) {
            const int nl = h * 32 + i;
            const int lab = lab_l[nl];
            const float f = lds[cw][nl];
            s0 += (lab == 0) ? f : 0.f;
            s1 += (lab == 1) ? f : 0.f;
            s2 += (lab == 2) ? f : 0.f;
            s3 += (lab == 3) ? f : 0.f;
        }
        cs[h][0][cw] = s0; cs[h][1][cw] = s1;
        cs[h][2][cw] = s2; cs[h][3][cw] = s3;
    }
    __syncthreads();
    if (t < 128) {
#pragma unroll
        for (int k = 0; k < 4; k++)
            atomicAdd(&G[k * CDIM + t], cs[0][k][t] + cs[1][k][t]);
    }

    // swizzled bf16 fragment writes:
    // frag (ctg*4+kk), element q*16+r holds F[ctg*16+r][kk*32+q*8+j]*FSCALE
    #pragma unroll
    for (int i = 0; i < 4; i++) {
        const int slot = i * 256 + t;
        const int f = slot >> 6, l = slot & 63;
        const int ctl = f >> 2, kk = f & 3;
        const int q = l >> 4, r = l & 15;
        const int nl = ctl * 16 + r;
        const int c0 = kk * 32 + q * 8;
        v8bf val;
#pragma unroll
        for (int j = 0; j < 8; j++) val[j] = (__bf16)(lds[c0 + j][nl] * FSCALE);
        const int ctg = (nbase >> 4) + ctl;
        swf[(ctg * 4 + kk) * 64 + l] = val;
    }
}

// Stage one 16-col tile (4 KB, contiguous in swf) into LDS via global_load_lds.
// Each wave copies its 1 KB quarter: per-lane global src, wave-uniform LDS dst
// (HW adds lane*16).
__device__ __forceinline__ void stage_tile(const v8bf* swf, __bf16* ldsbase,
                                           int ct, int wave, int lane)
{
    const char* g = (const char*)swf + ((size_t)ct << 12) + (wave << 10) + (lane << 4);
    char* l = (char*)ldsbase + (wave << 10);
    __builtin_amdgcn_global_load_lds(
        (__attribute__((address_space(1))) void*)(char*)g,
        (__attribute__((address_space(3))) void*)l, 16, 0, 0);
}

// Fused S = F F^T (bf16 MFMA) + exp2 row-sum. Full grid (no symmetry — R3's
// cross-XCD atomic ping-pong lesson). B staged through double-buffered LDS so
// A-frags stay register-resident; counted vmcnt keeps prefetch in flight
// across raw s_barriers. Partial row-sums stored (no atomics).
// Block = 4 waves; wave owns 64 rows; block covers 256 rows x 256 cols.
__global__ __launch_bounds__(256, 4) void k3_gemm_expsum(
    const v8bf* __restrict__ swf, float* __restrict__ part)
{
    __shared__ __align__(16) __bf16 bbuf[2][2048];   // 2 x 4 KB
    const int t = threadIdx.x;
    const int lane = t & 63;
    const int wave = t >> 6;
    const int rowblk = blockIdx.x & 31;    // 256 rows each
    const int colchunk = blockIdx.x >> 5;  // 256 cols each
    const int rowbase = rowblk * 256 + wave * 64;
    const int rt0 = rowbase >> 4;
    const int ct0 = colchunk * 16;

    // A fragments: 16 x v8bf = 64 VGPRs, resident for the whole kernel
    v8bf a[4][4];
#pragma unroll
    for (int tt = 0; tt < 4; tt++)
#pragma unroll
        for (int kk = 0; kk < 4; kk++)
            a[tt][kk] = swf[((rt0 + tt) * 4 + kk) * 64 + lane];

    stage_tile(swf, &bbuf[0][0], ct0, wave, lane);

    float rs[4][4];
#pragma unroll
    for (int tt = 0; tt < 4; tt++)
#pragma unroll
        for (int r = 0; r < 4; r++) rs[tt][r] = 0.f;

    for (int cl = 0; cl < 16; ++cl) {
        if (cl < 15) {
            stage_tile(swf, &bbuf[(cl + 1) & 1][0], ct0 + cl + 1, wave, lane);
            asm volatile("s_waitcnt vmcnt(1)" ::: "memory");  // cur staged; next stays in flight
        } else {
            asm volatile("s_waitcnt vmcnt(0)" ::: "memory");
        }
        __builtin_amdgcn_s_barrier();
        asm volatile("" ::: "memory");   // block load-hoist above the barrier

        const v8bf* bb = (const v8bf*)&bbuf[cl & 1][0];
        const v8bf b0 = bb[lane];
        const v8bf b1 = bb[64 + lane];
        const v8bf b2 = bb[128 + lane];
        const v8bf b3 = bb[192 + lane];
#pragma unroll
        for (int tt = 0; tt < 4; tt++) {
            f32x4 acc = {0.f, 0.f, 0.f, 0.f};
            acc = __builtin_amdgcn_mfma_f32_16x16x32_bf16(a[tt][0], b0, acc, 0, 0, 0);
            acc = __builtin_amdgcn_mfma_f32_16x16x32_bf16(a[tt][1], b1, acc, 0, 0, 0);
            acc = __builtin_amdgcn_mfma_f32_16x16x32_bf16(a[tt][2], b2, acc, 0, 0, 0);
            acc = __builtin_amdgcn_mfma_f32_16x16x32_bf16(a[tt][3], b3, acc, 0, 0, 0);
            // acc already = S * log2(e) thanks to FSCALE folding
#pragma unroll
            for (int r = 0; r < 4; r++)
                rs[tt][r] += __builtin_amdgcn_exp2f(acc[r]);
        }
        asm volatile("s_waitcnt lgkmcnt(0)" ::: "memory");  // LDS reads retired
        __builtin_amdgcn_s_barrier();                        // before overwrite next iter
    }

    // row-sums: reduce across the 16 lanes of each C/D column group
#pragma unroll
    for (int m = 1; m < 16; m <<= 1)
#pragma unroll
        for (int tt = 0; tt < 4; tt++)
#pragma unroll
            for (int r = 0; r < 4; r++)
                rs[tt][r] += __shfl_xor(rs[tt][r], m, 64);

    if ((lane & 15) == 0) {
        const int g = lane >> 4;
        float* dst = part + (size_t)colchunk * NPIX + rowbase;
#pragma unroll
        for (int tt = 0; tt < 4; tt++)
#pragma unroll
            for (int r = 0; r < 4; r++)
                dst[tt * 16 + g * 4 + r] = rs[tt][r];
    }
}

// Per-anchor loss. Block = 4 waves over 64 anchors (one anchor per lane,
// p-coalesced feats reads); each wave covers 32 channels; LDS combine;
// wave 0 sums the 32 rowsum partials; one atomicAdd per block.
__global__ __launch_bounds__(256) void k4_loss(
    const float* __restrict__ feats, const int* __restrict__ labels,
    const float* __restrict__ G, const int* __restrict__ counts,
    const float* __restrict__ part, float* __restrict__ acc)
{
    __shared__ float pd[4][64];
    const int t = threadIdx.x, lane = t & 63, w = t >> 6;
    const int n0 = blockIdx.x * 64;
    const int bp = n0 >> 10, p0 = n0 & 1023;
    const int bv = ((bp & 3) << 1) + (bp >> 2);
    const int p = p0 + lane;
    const int lab = labels[(bv << 10) + p];

    const float* src = feats + (((size_t)bv * CDIM + w * 32) << 10) + p;
    const float* g0p = G + w * 32;
    float dot = 0.f;
#pragma unroll 8
    for (int c = 0; c < 32; ++c) {
        const float f = src[(size_t)c << 10];
        const float g0 = g0p[c], g1 = g0p[CDIM + c];
        const float g2 = g0p[2 * CDIM + c], g3 = g0p[3 * CDIM + c];
        const float g = (lab == 1) ? g1 : (lab == 2) ? g2 : (lab == 3) ? g3 : g0;
        dot += f * g;
    }
    pd[w][lane] = dot;
    __syncthreads();
    if (w == 0) {
        float den = -EXPDIAG;
#pragma unroll 8
        for (int cc = 0; cc < 32; ++cc)
            den += part[(size_t)cc * NPIX + n0 + lane];
        const float d = pd[0][lane] + pd[1][lane] + pd[2][lane] + pd[3][lane];
        float loss = 0.f;
        if (lab != 0) {
            const float num = (d - 1.0f) * (1.0f / TEMP);
            const float cnt = (float)(counts[lab] - 1);
            loss = __builtin_amdgcn_logf(den) * LN2 - num / cnt;
        }
#pragma unroll
        for (int m = 1; m < 64; m <<= 1) loss += __shfl_xor(loss, m, 64);
        if (lane == 0) atomicAdd(acc, loss);
    }
}

__global__ void k5_final(const float* __restrict__ acc,
                         const int* __restrict__ counts,
                         float* __restrict__ out)
{
    const int nv = NPIX - counts[0];
    out[0] = (nv > 0) ? acc[0] / (float)nv : 0.0f;
}

extern "C" void kernel_launch(void* const* d_in, const int* in_sizes, int n_in,
                              void* d_out, int out_size, void* d_ws, size_t ws_size,
                              hipStream_t stream) {
    const float* feats = (const float*)d_in[0];
    const int* labels = (const int*)d_in[1];
    float* out = (float*)d_out;
    float* W = (float*)d_ws;

    float* G      = W + OFF_G;
    int*   counts = (int*)(W + OFF_COUNTS);
    float* acc    = W + OFF_ACC;
    float* part   = W + OFF_PART;
    v8bf*  swf    = (v8bf*)(W + OFF_SWF);

    k0_zero<<<(OFF_ZERON + 255) / 256, 256, 0, stream>>>(W);
    k1_build<<<128, 256, 0, stream>>>(feats, labels, swf, G, counts);
    k3_gemm_expsum<<<32 * 32, 256, 0, stream>>>(swf, part);
    k4_loss<<<128, 256, 0, stream>>>(feats, labels, G, counts, part, acc);
    k5_final<<<1, 1, 0, stream>>>(acc, counts, out);
}

// Round 6
// 79.950 us; speedup vs baseline: 1.3467x; 1.3467x over previous
//
#include <hip/hip_runtime.h>

#define TEMP 0.7f
#define LOG2E 1.4426950408889634f
#define LN2 0.6931471805599453f
#define NPIX 8192
#define CDIM 128
// sqrt(LOG2E / TEMP): fold exp2-conversion + temperature into bf16 operands
#define FSCALE 1.4356161f
// exp(1/TEMP) = exp(diag) since features are L2-normalized (|F|^2 == 1)
#define EXPDIAG 4.1727352f

typedef __bf16 v8bf __attribute__((ext_vector_type(8)));
typedef float f32x4 __attribute__((ext_vector_type(4)));

// workspace layout (float offsets)
#define OFF_G      0            // 4*128 floats
#define OFF_COUNTS 512          // int[4]
#define OFF_ACC    516          // 1 float
#define OFF_ZERON  520          // zero the first OFF_ZERON floats
#define OFF_PART   1024         // 16 * 8192 floats (per-colchunk rowsum partials)
#define OFF_SWF    (1024 + 16 * NPIX)   // NPIX*CDIM bf16

__global__ __launch_bounds__(256) void k0_zero(float* __restrict__ w) {
    const int i = blockIdx.x * 256 + threadIdx.x;
    if (i < OFF_ZERON) w[i] = 0.0f;
}

// Transpose-build: coalesced feats reads -> LDS tile (128c x 32p, pad 33),
// then emit swizzled bf16 MFMA fragments, class sums G, counts.
// 256 blocks (1/CU), all LDS access <=2-way bank aliasing (free).
__global__ __launch_bounds__(256) void k1_build(
    const float* __restrict__ feats, const int* __restrict__ labels,
    v8bf* __restrict__ swf, float* __restrict__ G, int* __restrict__ counts)
{
    __shared__ float lds[128][33];
    __shared__ int lab_l[32];
    __shared__ float cs[2][4][128];

    const int t = threadIdx.x;
    const int bp = blockIdx.x >> 5;   // b' = row-block in concat order, 0..7
    const int pc = blockIdx.x & 31;   // 32-pixel chunk
    const int b = bp & 3, v = bp >> 2;
    const int bv = b * 2 + v;         // index into feats/labels batch dim
    const int p0 = pc * 32;
    const int nbase = bp * 1024 + p0;

    const float* src = feats + (size_t)bv * CDIM * 1024 + p0;
    const int px = t & 31, c8 = t >> 5;   // 8 channels per pass
#pragma unroll
    for (int i = 0; i < 16; i++) {
        const int c = i * 8 + c8;
        lds[c][px] = src[c * 1024 + px];
    }
    // labels + counts
    if (t < 32) {
        const int lab = labels[bv * 1024 + p0 + t];
        lab_l[t] = lab;
#pragma unroll
        for (int k = 0; k < 4; k++) {
            unsigned long long m = __ballot(lab == k);
            if (t == 0) atomicAdd(&counts[k], (int)__popcll(m));
        }
    }
    __syncthreads();

    // per-class partial sums over this block's 32 pixels
    {
        const int cw = t & 127, h = t >> 7;
        float s0 = 0.f, s1 = 0.f, s2 = 0.f, s3 = 0.f;
#pragma unroll
        for (int i = 0; i < 16; i++) {
            const int nl = h * 16 + i;
            const int lab = lab_l[nl];
            const float f = lds[cw][nl];
            s0 += (lab == 0) ? f : 0.f;
            s1 += (lab == 1) ? f : 0.f;
            s2 += (lab == 2) ? f : 0.f;
            s3 += (lab == 3) ? f : 0.f;
        }
        cs[h][0][cw] = s0; cs[h][1][cw] = s1;
        cs[h][2][cw] = s2; cs[h][3][cw] = s3;
    }
    __syncthreads();
    if (t < 128) {
#pragma unroll
        for (int k = 0; k < 4; k++)
            atomicAdd(&G[k * CDIM + t], cs[0][k][t] + cs[1][k][t]);
    }

    // swizzled bf16 fragment writes:
    // frag (ctg*4+kk), element q*16+r holds F[ctg*16+r][kk*32+q*8+j]*FSCALE
#pragma unroll
    for (int i2 = 0; i2 < 2; i2++) {
        const int slot = i2 * 256 + t;
        const int f = slot >> 6, l = slot & 63;
        const int ctl = f >> 2, kk = f & 3;
        const int q = l >> 4, r = l & 15;
        const int nl = ctl * 16 + r;
        const int c0 = kk * 32 + q * 8;
        v8bf val;
#pragma unroll
        for (int j = 0; j < 8; j++) val[j] = (__bf16)(lds[c0 + j][nl] * FSCALE);
        const int ctg = (nbase >> 4) + ctl;
        swf[(ctg * 4 + kk) * 64 + l] = val;
    }
}

// Fused S = F F^T (bf16 MFMA) + exp2 row-sum. No LDS, no inline asm (R4's
// scratch-spill lesson): swf is 2 MB = L2-resident, the block's 4 waves read
// identical B addresses (L1 dedups). A-frags register-resident under
// __launch_bounds__(256,2) (R3 evidence: VGPR=128, no scratch).
// Wave owns 64 rows; block covers 256 rows x 512 cols; two independent
// col-tiles per fully-unrolled iteration for load-latency-hiding ILP.
// Partial row-sums stored (no atomics, no contention).
__global__ __launch_bounds__(256, 2) void k3_gemm_expsum(
    const v8bf* __restrict__ swf, float* __restrict__ part)
{
    const int lane = threadIdx.x & 63;
    const int wave = threadIdx.x >> 6;
    const int rowblk = blockIdx.x & 31;    // 32 row-blocks of 256
    const int colchunk = blockIdx.x >> 5;  // 16 col-chunks of 512
    const int rowbase = rowblk * 256 + wave * 64;
    const int rt0 = rowbase >> 4;
    const int ct0 = colchunk * 32;         // 32 col-tiles of 16

    // A fragments: 16 x v8bf = 64 VGPRs, resident for the whole kernel
    v8bf a[4][4];
#pragma unroll
    for (int tt = 0; tt < 4; tt++)
#pragma unroll
        for (int kk = 0; kk < 4; kk++)
            a[tt][kk] = swf[((rt0 + tt) * 4 + kk) * 64 + lane];

    float rs[4][4];
#pragma unroll
    for (int tt = 0; tt < 4; tt++)
#pragma unroll
        for (int r = 0; r < 4; r++) rs[tt][r] = 0.f;

#pragma unroll
    for (int it = 0; it < 16; ++it) {
        const v8bf* pA = swf + (size_t)(ct0 + it) * 256 + lane;
        const v8bf* pB = swf + (size_t)(ct0 + 16 + it) * 256 + lane;
        const v8bf bA0 = pA[0], bA1 = pA[64], bA2 = pA[128], bA3 = pA[192];
        const v8bf bB0 = pB[0], bB1 = pB[64], bB2 = pB[128], bB3 = pB[192];
#pragma unroll
        for (int tt = 0; tt < 4; tt++) {
            f32x4 accA = {0.f, 0.f, 0.f, 0.f};
            f32x4 accB = {0.f, 0.f, 0.f, 0.f};
            accA = __builtin_amdgcn_mfma_f32_16x16x32_bf16(a[tt][0], bA0, accA, 0, 0, 0);
            accA = __builtin_amdgcn_mfma_f32_16x16x32_bf16(a[tt][1], bA1, accA, 0, 0, 0);
            accA = __builtin_amdgcn_mfma_f32_16x16x32_bf16(a[tt][2], bA2, accA, 0, 0, 0);
            accA = __builtin_amdgcn_mfma_f32_16x16x32_bf16(a[tt][3], bA3, accA, 0, 0, 0);
            accB = __builtin_amdgcn_mfma_f32_16x16x32_bf16(a[tt][0], bB0, accB, 0, 0, 0);
            accB = __builtin_amdgcn_mfma_f32_16x16x32_bf16(a[tt][1], bB1, accB, 0, 0, 0);
            accB = __builtin_amdgcn_mfma_f32_16x16x32_bf16(a[tt][2], bB2, accB, 0, 0, 0);
            accB = __builtin_amdgcn_mfma_f32_16x16x32_bf16(a[tt][3], bB3, accB, 0, 0, 0);
            // acc already = S * log2(e) thanks to FSCALE folding
#pragma unroll
            for (int r = 0; r < 4; r++)
                rs[tt][r] += __builtin_amdgcn_exp2f(accA[r])
                           + __builtin_amdgcn_exp2f(accB[r]);
        }
    }

    // row-sums: reduce across the 16 lanes of each C/D column group
#pragma unroll
    for (int m = 1; m < 16; m <<= 1)
#pragma unroll
        for (int tt = 0; tt < 4; tt++)
#pragma unroll
            for (int r = 0; r < 4; r++)
                rs[tt][r] += __shfl_xor(rs[tt][r], m, 64);

    if ((lane & 15) == 0) {
        const int g = lane >> 4;
        float* dst = part + (size_t)colchunk * NPIX + rowbase;
#pragma unroll
        for (int tt = 0; tt < 4; tt++)
#pragma unroll
            for (int r = 0; r < 4; r++)
                dst[tt * 16 + g * 4 + r] = rs[tt][r];
    }
}

// Per-anchor loss. Block = 4 waves over 64 anchors (one anchor per lane,
// p-coalesced feats reads); each wave covers 32 channels; LDS combine;
// wave 0 sums the 16 rowsum partials; one atomicAdd per block.
__global__ __launch_bounds__(256) void k4_loss(
    const float* __restrict__ feats, const int* __restrict__ labels,
    const float* __restrict__ G, const int* __restrict__ counts,
    const float* __restrict__ part, float* __restrict__ acc)
{
    __shared__ float pd[4][64];
    const int t = threadIdx.x, lane = t & 63, w = t >> 6;
    const int n0 = blockIdx.x * 64;
    const int bp = n0 >> 10, p0 = n0 & 1023;
    const int bv = ((bp & 3) << 1) + (bp >> 2);
    const int p = p0 + lane;
    const int lab = labels[(bv << 10) + p];

    const float* src = feats + (((size_t)bv * CDIM + w * 32) << 10) + p;
    const float* g0p = G + w * 32;
    float dot = 0.f;
#pragma unroll 8
    for (int c = 0; c < 32; ++c) {
        const float f = src[(size_t)c << 10];
        const float g0 = g0p[c], g1 = g0p[CDIM + c];
        const float g2 = g0p[2 * CDIM + c], g3 = g0p[3 * CDIM + c];
        const float g = (lab == 1) ? g1 : (lab == 2) ? g2 : (lab == 3) ? g3 : g0;
        dot += f * g;
    }
    pd[w][lane] = dot;
    __syncthreads();
    if (w == 0) {
        float den = -EXPDIAG;
#pragma unroll
        for (int cc = 0; cc < 16; ++cc)
            den += part[(size_t)cc * NPIX + n0 + lane];
        const float d = pd[0][lane] + pd[1][lane] + pd[2][lane] + pd[3][lane];
        float loss = 0.f;
        if (lab != 0) {
            const float num = (d - 1.0f) * (1.0f / TEMP);
            const float cnt = (float)(counts[lab] - 1);
            loss = __builtin_amdgcn_logf(den) * LN2 - num / cnt;
        }
#pragma unroll
        for (int m = 1; m < 64; m <<= 1) loss += __shfl_xor(loss, m, 64);
        if (lane == 0) atomicAdd(acc, loss);
    }
}

__global__ void k5_final(const float* __restrict__ acc,
                         const int* __restrict__ counts,
                         float* __restrict__ out)
{
    const int nv = NPIX - counts[0];
    out[0] = (nv > 0) ? acc[0] / (float)nv : 0.0f;
}

extern "C" void kernel_launch(void* const* d_in, const int* in_sizes, int n_in,
                              void* d_out, int out_size, void* d_ws, size_t ws_size,
                              hipStream_t stream) {
    const float* feats = (const float*)d_in[0];
    const int* labels = (const int*)d_in[1];
    float* out = (float*)d_out;
    float* W = (float*)d_ws;

    float* G      = W + OFF_G;
    int*   counts = (int*)(W + OFF_COUNTS);
    float* acc    = W + OFF_ACC;
    float* part   = W + OFF_PART;
    v8bf*  swf    = (v8bf*)(W + OFF_SWF);

    k0_zero<<<(OFF_ZERON + 255) / 256, 256, 0, stream>>>(W);
    k1_build<<<256, 256, 0, stream>>>(feats, labels, swf, G, counts);
    k3_gemm_expsum<<<32 * 16, 256, 0, stream>>>(swf, part);
    k4_loss<<<128, 256, 0, stream>>>(feats, labels, G, counts, part, acc);
    k5_final<<<1, 1, 0, stream>>>(acc, counts, out);
}

// Round 7
// 56.049 us; speedup vs baseline: 1.9210x; 1.4264x over previous
//
#include <hip/hip_runtime.h>

#define TEMP 0.7f
#define LOG2E 1.4426950408889634f
#define LN2 0.6931471805599453f
#define NPIX 8192
#define CDIM 128
// sqrt(LOG2E / TEMP): fold exp2-conversion + temperature into bf16 operands
#define FSCALE 1.4356161f
// exp(1/TEMP) = exp(diag) since features are L2-normalized (|F|^2 == 1)
#define EXPDIAG 4.1727352f

typedef __bf16 v8bf __attribute__((ext_vector_type(8)));
typedef float f32x4 __attribute__((ext_vector_type(4)));

// workspace layout (float offsets)
#define OFF_G      0            // 4*128 floats
#define OFF_COUNTS 512          // int[4]
#define OFF_ACC    516          // 1 float
#define OFF_DONE   517          // 1 int
#define OFF_ZERON  520          // zero the first OFF_ZERON floats
#define OFF_PART   1024         // 32 * 8192 floats (per-colchunk rowsum partials)
#define OFF_SWF    (1024 + 32 * NPIX)   // NPIX*CDIM bf16

__global__ __launch_bounds__(256) void k0_zero(float* __restrict__ w) {
    const int i = blockIdx.x * 256 + threadIdx.x;
    if (i < OFF_ZERON) w[i] = 0.0f;
}

// Transpose-build: coalesced feats reads -> LDS tile (128c x 32p, pad 33),
// then emit swizzled bf16 MFMA fragments, class sums G, counts.
// 256 blocks (1/CU), all LDS access <=2-way bank aliasing (free).
__global__ __launch_bounds__(256) void k1_build(
    const float* __restrict__ feats, const int* __restrict__ labels,
    v8bf* __restrict__ swf, float* __restrict__ G, int* __restrict__ counts)
{
    __shared__ float lds[128][33];
    __shared__ int lab_l[32];
    __shared__ float cs[2][4][128];

    const int t = threadIdx.x;
    const int bp = blockIdx.x >> 5;   // b' = row-block in concat order, 0..7
    const int pc = blockIdx.x & 31;   // 32-pixel chunk
    const int b = bp & 3, v = bp >> 2;
    const int bv = b * 2 + v;         // index into feats/labels batch dim
    const int p0 = pc * 32;
    const int nbase = bp * 1024 + p0;

    const float* src = feats + (size_t)bv * CDIM * 1024 + p0;
    const int px = t & 31, c8 = t >> 5;   // 8 channels per pass
#pragma unroll
    for (int i = 0; i < 16; i++) {
        const int c = i * 8 + c8;
        lds[c][px] = src[c * 1024 + px];
    }
    // labels + counts
    if (t < 32) {
        const int lab = labels[bv * 1024 + p0 + t];
        lab_l[t] = lab;
#pragma unroll
        for (int k = 0; k < 4; k++) {
            unsigned long long m = __ballot(lab == k);
            if (t == 0) atomicAdd(&counts[k], (int)__popcll(m));
        }
    }
    __syncthreads();

    // per-class partial sums over this block's 32 pixels
    {
        const int cw = t & 127, h = t >> 7;
        float s0 = 0.f, s1 = 0.f, s2 = 0.f, s3 = 0.f;
#pragma unroll
        for (int i = 0; i < 16; i++) {
            const int nl = h * 16 + i;
            const int lab = lab_l[nl];
            const float f = lds[cw][nl];
            s0 += (lab == 0) ? f : 0.f;
            s1 += (lab == 1) ? f : 0.f;
            s2 += (lab == 2) ? f : 0.f;
            s3 += (lab == 3) ? f : 0.f;
        }
        cs[h][0][cw] = s0; cs[h][1][cw] = s1;
        cs[h][2][cw] = s2; cs[h][3][cw] = s3;
    }
    __syncthreads();
    if (t < 128) {
#pragma unroll
        for (int k = 0; k < 4; k++)
            atomicAdd(&G[k * CDIM + t], cs[0][k][t] + cs[1][k][t]);
    }

    // swizzled bf16 fragment writes:
    // frag (ctg*4+kk), element q*16+r holds F[ctg*16+r][kk*32+q*8+j]*FSCALE
#pragma unroll
    for (int i2 = 0; i2 < 2; i2++) {
        const int slot = i2 * 256 + t;
        const int f = slot >> 6, l = slot & 63;
        const int ctl = f >> 2, kk = f & 3;
        const int q = l >> 4, r = l & 15;
        const int nl = ctl * 16 + r;
        const int c0 = kk * 32 + q * 8;
        v8bf val;
#pragma unroll
        for (int j = 0; j < 8; j++) val[j] = (__bf16)(lds[c0 + j][nl] * FSCALE);
        const int ctg = (nbase >> 4) + ctl;
        swf[(ctg * 4 + kk) * 64 + l] = val;
    }
}

// Stage one 16-col tile (4 KB, contiguous in swf) into LDS via global_load_lds.
// Each thread copies 16 B: per-lane global src; LDS dst is wave-uniform base,
// HW adds lane*16. Data never touches VGPRs.
__device__ __forceinline__ void stage_tile(const v8bf* swf, __bf16* ldsbase,
                                           int ct, int wave, int lane)
{
    const char* g = (const char*)swf + ((size_t)ct << 12) + (wave << 10) + (lane << 4);
    char* l = (char*)ldsbase + (wave << 10);
    __builtin_amdgcn_global_load_lds(
        (__attribute__((address_space(1))) void*)(char*)g,
        (__attribute__((address_space(3))) void*)l, 16, 0, 0);
}

// Fused S = F F^T (bf16 MFMA) + exp2 row-sum, m97-style:
// A-frags register-resident (loop-invariant, 64 VGPR); B tiles flow through
// double-buffered LDS via global_load_lds (zero VGPR data path); plain
// __syncthreads (no inline asm — R4/R5 scratch-spill lessons); rolled col
// loop so the scheduler can't merge iterations and blow the live set.
// Block = 4 waves; wave owns 64 rows; block covers 256 rows x 256 cols.
// Partial row-sums stored (no atomics, no contention).
__global__ __launch_bounds__(256, 2) void k3_gemm_expsum(
    const v8bf* __restrict__ swf, float* __restrict__ part)
{
    __shared__ __align__(16) __bf16 bbuf[2][2048];   // 2 x 4 KB
    const int t = threadIdx.x;
    const int lane = t & 63;
    const int wave = t >> 6;
    const int rowblk = blockIdx.x & 31;    // 32 row-blocks of 256
    const int colchunk = blockIdx.x >> 5;  // 32 col-chunks of 256
    const int rowbase = rowblk * 256 + wave * 64;
    const int rt0 = rowbase >> 4;
    const int ct0 = colchunk * 16;         // 16 col-tiles of 16

    // A fragments: 16 x v8bf = 64 VGPRs, resident for the whole kernel
    v8bf a[4][4];
#pragma unroll
    for (int tt = 0; tt < 4; tt++)
#pragma unroll
        for (int kk = 0; kk < 4; kk++)
            a[tt][kk] = swf[((rt0 + tt) * 4 + kk) * 64 + lane];

    float rs[4][4];
#pragma unroll
    for (int tt = 0; tt < 4; tt++)
#pragma unroll
        for (int r = 0; r < 4; r++) rs[tt][r] = 0.f;

    stage_tile(swf, &bbuf[0][0], ct0, wave, lane);
    __syncthreads();

#pragma unroll 1
    for (int it = 0; it < 16; ++it) {
        if (it < 15)
            stage_tile(swf, &bbuf[(it + 1) & 1][0], ct0 + it + 1, wave, lane);

        const v8bf* bb = (const v8bf*)&bbuf[it & 1][0];
        const v8bf b0 = bb[lane];
        const v8bf b1 = bb[64 + lane];
        const v8bf b2 = bb[128 + lane];
        const v8bf b3 = bb[192 + lane];
#pragma unroll
        for (int tt = 0; tt < 4; tt++) {
            f32x4 acc = {0.f, 0.f, 0.f, 0.f};
            acc = __builtin_amdgcn_mfma_f32_16x16x32_bf16(a[tt][0], b0, acc, 0, 0, 0);
            acc = __builtin_amdgcn_mfma_f32_16x16x32_bf16(a[tt][1], b1, acc, 0, 0, 0);
            acc = __builtin_amdgcn_mfma_f32_16x16x32_bf16(a[tt][2], b2, acc, 0, 0, 0);
            acc = __builtin_amdgcn_mfma_f32_16x16x32_bf16(a[tt][3], b3, acc, 0, 0, 0);
            // acc already = S * log2(e) thanks to FSCALE folding
#pragma unroll
            for (int r = 0; r < 4; r++)
                rs[tt][r] += __builtin_amdgcn_exp2f(acc[r]);
        }
        // guarantees: (a) all waves done reading bbuf[it&1] before it's
        // restaged at it+2; (b) stage of it+1 complete (vmcnt drained).
        __syncthreads();
    }

    // row-sums: reduce across the 16 lanes of each C/D column group
#pragma unroll
    for (int m = 1; m < 16; m <<= 1)
#pragma unroll
        for (int tt = 0; tt < 4; tt++)
#pragma unroll
            for (int r = 0; r < 4; r++)
                rs[tt][r] += __shfl_xor(rs[tt][r], m, 64);

    if ((lane & 15) == 0) {
        const int g = lane >> 4;
        float* dst = part + (size_t)colchunk * NPIX + rowbase;
#pragma unroll
        for (int tt = 0; tt < 4; tt++)
#pragma unroll
            for (int r = 0; r < 4; r++)
                dst[tt * 16 + g * 4 + r] = rs[tt][r];
    }
}

// Per-anchor loss + final divide in the last block (done-counter).
// Block = 4 waves over 64 anchors (one anchor per lane, p-coalesced feats
// reads); each wave covers 32 channels; LDS combine; wave 0 sums the 32
// rowsum partials; one atomicAdd per block.
__global__ __launch_bounds__(256) void k4_loss(
    const float* __restrict__ feats, const int* __restrict__ labels,
    const float* __restrict__ G, const int* __restrict__ counts,
    const float* __restrict__ part, float* __restrict__ acc,
    int* __restrict__ done, float* __restrict__ out)
{
    __shared__ float pd[4][64];
    const int t = threadIdx.x, lane = t & 63, w = t >> 6;
    const int n0 = blockIdx.x * 64;
    const int bp = n0 >> 10, p0 = n0 & 1023;
    const int bv = ((bp & 3) << 1) + (bp >> 2);
    const int p = p0 + lane;
    const int lab = labels[(bv << 10) + p];

    const float* src = feats + (((size_t)bv * CDIM + w * 32) << 10) + p;
    const float* g0p = G + w * 32;
    float dot = 0.f;
#pragma unroll 8
    for (int c = 0; c < 32; ++c) {
        const float f = src[(size_t)c << 10];
        const float g0 = g0p[c], g1 = g0p[CDIM + c];
        const float g2 = g0p[2 * CDIM + c], g3 = g0p[3 * CDIM + c];
        const float g = (lab == 1) ? g1 : (lab == 2) ? g2 : (lab == 3) ? g3 : g0;
        dot += f * g;
    }
    pd[w][lane] = dot;
    __syncthreads();
    if (w == 0) {
        float den = -EXPDIAG;
#pragma unroll 8
        for (int cc = 0; cc < 32; ++cc)
            den += part[(size_t)cc * NPIX + n0 + lane];
        const float d = pd[0][lane] + pd[1][lane] + pd[2][lane] + pd[3][lane];
        float loss = 0.f;
        if (lab != 0) {
            const float num = (d - 1.0f) * (1.0f / TEMP);
            const float cnt = (float)(counts[lab] - 1);
            loss = __builtin_amdgcn_logf(den) * LN2 - num / cnt;
        }
#pragma unroll
        for (int m = 1; m < 64; m <<= 1) loss += __shfl_xor(loss, m, 64);
        if (lane == 0) {
            atomicAdd(acc, loss);
            __threadfence();
            const int old = atomicAdd(done, 1);
            if (old == 127) {
                const float tot = atomicAdd(acc, 0.0f);
                const int nv = NPIX - counts[0];
                out[0] = (nv > 0) ? tot / (float)nv : 0.0f;
            }
        }
    }
}

extern "C" void kernel_launch(void* const* d_in, const int* in_sizes, int n_in,
                              void* d_out, int out_size, void* d_ws, size_t ws_size,
                              hipStream_t stream) {
    const float* feats = (const float*)d_in[0];
    const int* labels = (const int*)d_in[1];
    float* out = (float*)d_out;
    float* W = (float*)d_ws;

    float* G      = W + OFF_G;
    int*   counts = (int*)(W + OFF_COUNTS);
    float* acc    = W + OFF_ACC;
    int*   done   = (int*)(W + OFF_DONE);
    float* part   = W + OFF_PART;
    v8bf*  swf    = (v8bf*)(W + OFF_SWF);

    k0_zero<<<3, 256, 0, stream>>>(W);
    k1_build<<<256, 256, 0, stream>>>(feats, labels, swf, G, counts);
    k3_gemm_expsum<<<32 * 32, 256, 0, stream>>>(swf, part);
    k4_loss<<<128, 256, 0, stream>>>(feats, labels, G, counts, part, acc, done, out);
}

// Round 8
// 55.387 us; speedup vs baseline: 1.9440x; 1.0119x over previous
//
#include <hip/hip_runtime.h>

#define TEMP 0.7f
#define LOG2E 1.4426950408889634f
#define LN2 0.6931471805599453f
#define NPIX 8192
#define CDIM 128
#define NCHUNK 64               // col-chunks of 128 cols
// sqrt(LOG2E / TEMP): fold exp2-conversion + temperature into bf16 operands
#define FSCALE 1.4356161f
// exp(1/TEMP) = exp(diag) since features are L2-normalized (|F|^2 == 1)
#define EXPDIAG 4.1727352f

typedef __bf16 v8bf __attribute__((ext_vector_type(8)));
typedef float f32x4 __attribute__((ext_vector_type(4)));

// workspace layout (float offsets)
#define OFF_G      0            // 4*128 floats
#define OFF_COUNTS 512          // int[4]
#define OFF_ACC    516          // 1 float
#define OFF_DONE   517          // 1 int
#define OFF_ZERON  520          // zero the first OFF_ZERON floats
#define OFF_PART   1024         // NCHUNK * 8192 floats (rowsum partials)
#define OFF_SWF    (1024 + NCHUNK * NPIX)   // NPIX*CDIM bf16

__global__ __launch_bounds__(256) void k0_zero(float* __restrict__ w) {
    const int i = blockIdx.x * 256 + threadIdx.x;
    if (i < OFF_ZERON) w[i] = 0.0f;
}

// Transpose-build: coalesced feats reads -> LDS tile (128c x 32p, pad 33),
// then emit swizzled bf16 MFMA fragments, class sums G, counts.
// 256 blocks (1/CU), all LDS access <=2-way bank aliasing (free).
__global__ __launch_bounds__(256) void k1_build(
    const float* __restrict__ feats, const int* __restrict__ labels,
    v8bf* __restrict__ swf, float* __restrict__ G, int* __restrict__ counts)
{
    __shared__ float lds[128][33];
    __shared__ int lab_l[32];
    __shared__ float cs[2][4][128];

    const int t = threadIdx.x;
    const int bp = blockIdx.x >> 5;   // b' = row-block in concat order, 0..7
    const int pc = blockIdx.x & 31;   // 32-pixel chunk
    const int b = bp & 3, v = bp >> 2;
    const int bv = b * 2 + v;         // index into feats/labels batch dim
    const int p0 = pc * 32;
    const int nbase = bp * 1024 + p0;

    const float* src = feats + (size_t)bv * CDIM * 1024 + p0;
    const int px = t & 31, c8 = t >> 5;   // 8 channels per pass
#pragma unroll
    for (int i = 0; i < 16; i++) {
        const int c = i * 8 + c8;
        lds[c][px] = src[c * 1024 + px];
    }
    // labels + counts
    if (t < 32) {
        const int lab = labels[bv * 1024 + p0 + t];
        lab_l[t] = lab;
#pragma unroll
        for (int k = 0; k < 4; k++) {
            unsigned long long m = __ballot(lab == k);
            if (t == 0) atomicAdd(&counts[k], (int)__popcll(m));
        }
    }
    __syncthreads();

    // per-class partial sums over this block's 32 pixels
    {
        const int cw = t & 127, h = t >> 7;
        float s0 = 0.f, s1 = 0.f, s2 = 0.f, s3 = 0.f;
#pragma unroll
        for (int i = 0; i < 16; i++) {
            const int nl = h * 16 + i;
            const int lab = lab_l[nl];
            const float f = lds[cw][nl];
            s0 += (lab == 0) ? f : 0.f;
            s1 += (lab == 1) ? f : 0.f;
            s2 += (lab == 2) ? f : 0.f;
            s3 += (lab == 3) ? f : 0.f;
        }
        cs[h][0][cw] = s0; cs[h][1][cw] = s1;
        cs[h][2][cw] = s2; cs[h][3][cw] = s3;
    }
    __syncthreads();
    if (t < 128) {
#pragma unroll
        for (int k = 0; k < 4; k++)
            atomicAdd(&G[k * CDIM + t], cs[0][k][t] + cs[1][k][t]);
    }

    // swizzled bf16 fragment writes:
    // frag (ctg*4+kk), element q*16+r holds F[ctg*16+r][kk*32+q*8+j]*FSCALE
#pragma unroll
    for (int i2 = 0; i2 < 2; i2++) {
        const int slot = i2 * 256 + t;
        const int f = slot >> 6, l = slot & 63;
        const int ctl = f >> 2, kk = f & 3;
        const int q = l >> 4, r = l & 15;
        const int nl = ctl * 16 + r;
        const int c0 = kk * 32 + q * 8;
        v8bf val;
#pragma unroll
        for (int j = 0; j < 8; j++) val[j] = (__bf16)(lds[c0 + j][nl] * FSCALE);
        const int ctg = (nbase >> 4) + ctl;
        swf[(ctg * 4 + kk) * 64 + l] = val;
    }
}

// Stage one 16-col tile (4 KB, contiguous in swf) into LDS via global_load_lds.
// Each thread copies 16 B: per-lane global src; LDS dst is wave-uniform base,
// HW adds lane*16. Data never touches VGPRs.
__device__ __forceinline__ void stage_tile(const v8bf* swf, __bf16* ldsbase,
                                           int ct, int wave, int lane)
{
    const char* g = (const char*)swf + ((size_t)ct << 12) + (wave << 10) + (lane << 4);
    char* l = (char*)ldsbase + (wave << 10);
    __builtin_amdgcn_global_load_lds(
        (__attribute__((address_space(1))) void*)(char*)g,
        (__attribute__((address_space(3))) void*)l, 16, 0, 0);
}

// Fused S = F F^T (bf16 MFMA) + exp2 row-sum, barrier-free main loop:
// the block's whole 32 KB B-panel is staged into LDS ONCE (global_load_lds,
// zero VGPR), one __syncthreads, then 8 iterations of ds_read+MFMA+exp2 with
// NO barriers — TLP (4 blocks/CU target) + ILP hide all latency.
// A-frags register-resident (64 VGPR, loop-invariant).
// Block = 4 waves; wave owns 64 rows; block covers 256 rows x 128 cols.
// Partial row-sums stored (no atomics, no contention).
__global__ __launch_bounds__(256, 2) void k3_gemm_expsum(
    const v8bf* __restrict__ swf, float* __restrict__ part)
{
    __shared__ __align__(16) __bf16 bbuf[8][2048];   // 32 KB B-panel
    const int t = threadIdx.x;
    const int lane = t & 63;
    const int wave = t >> 6;
    const int rowblk = blockIdx.x & 31;    // 32 row-blocks of 256 rows
    const int colchunk = blockIdx.x >> 5;  // 64 col-chunks of 128 cols
    const int rowbase = rowblk * 256 + wave * 64;
    const int rt0 = rowbase >> 4;
    const int ct0 = colchunk * 8;          // 8 col-tiles of 16

    // stage the whole B-panel (8 x 4 KB), data never touches VGPRs
#pragma unroll
    for (int j = 0; j < 8; j++)
        stage_tile(swf, &bbuf[j][0], ct0 + j, wave, lane);

    // A fragments: 16 x v8bf = 64 VGPRs, resident for the whole kernel
    // (issued after the stages so all global latency overlaps)
    v8bf a[4][4];
#pragma unroll
    for (int tt = 0; tt < 4; tt++)
#pragma unroll
        for (int kk = 0; kk < 4; kk++)
            a[tt][kk] = swf[((rt0 + tt) * 4 + kk) * 64 + lane];

    float rs[4][4];
#pragma unroll
    for (int tt = 0; tt < 4; tt++)
#pragma unroll
        for (int r = 0; r < 4; r++) rs[tt][r] = 0.f;

    __syncthreads();   // panel staged; no further barriers

#pragma unroll 2
    for (int it = 0; it < 8; ++it) {
        const v8bf* bb = (const v8bf*)&bbuf[it][0];
        const v8bf b0 = bb[lane];
        const v8bf b1 = bb[64 + lane];
        const v8bf b2 = bb[128 + lane];
        const v8bf b3 = bb[192 + lane];
#pragma unroll
        for (int tt = 0; tt < 4; tt++) {
            f32x4 acc = {0.f, 0.f, 0.f, 0.f};
            acc = __builtin_amdgcn_mfma_f32_16x16x32_bf16(a[tt][0], b0, acc, 0, 0, 0);
            acc = __builtin_amdgcn_mfma_f32_16x16x32_bf16(a[tt][1], b1, acc, 0, 0, 0);
            acc = __builtin_amdgcn_mfma_f32_16x16x32_bf16(a[tt][2], b2, acc, 0, 0, 0);
            acc = __builtin_amdgcn_mfma_f32_16x16x32_bf16(a[tt][3], b3, acc, 0, 0, 0);
            // acc already = S * log2(e) thanks to FSCALE folding
#pragma unroll
            for (int r = 0; r < 4; r++)
                rs[tt][r] += __builtin_amdgcn_exp2f(acc[r]);
        }
    }

    // row-sums: reduce across the 16 lanes of each C/D column group
#pragma unroll
    for (int m = 1; m < 16; m <<= 1)
#pragma unroll
        for (int tt = 0; tt < 4; tt++)
#pragma unroll
            for (int r = 0; r < 4; r++)
                rs[tt][r] += __shfl_xor(rs[tt][r], m, 64);

    if ((lane & 15) == 0) {
        const int g = lane >> 4;
        float* dst = part + (size_t)colchunk * NPIX + rowbase;
#pragma unroll
        for (int tt = 0; tt < 4; tt++)
#pragma unroll
            for (int r = 0; r < 4; r++)
                dst[tt * 16 + g * 4 + r] = rs[tt][r];
    }
}

// Per-anchor loss + final divide in the last block (done-counter).
// Block = 4 waves over 64 anchors (one anchor per lane). Each wave sums 16
// of the 64 rowsum partials AND dots 32 of the 128 channels; LDS combine;
// one atomicAdd per block.
__global__ __launch_bounds__(256) void k4_loss(
    const float* __restrict__ feats, const int* __restrict__ labels,
    const float* __restrict__ G, const int* __restrict__ counts,
    const float* __restrict__ part, float* __restrict__ acc,
    int* __restrict__ done, float* __restrict__ out)
{
    __shared__ float pd[4][64];
    __shared__ float pq[4][64];
    const int t = threadIdx.x, lane = t & 63, w = t >> 6;
    const int n0 = blockIdx.x * 64;
    const int bp = n0 >> 10, p0 = n0 & 1023;
    const int bv = ((bp & 3) << 1) + (bp >> 2);
    const int p = p0 + lane;
    const int lab = labels[(bv << 10) + p];

    const float* src = feats + (((size_t)bv * CDIM + w * 32) << 10) + p;
    const float* g0p = G + w * 32;
    float dot = 0.f;
#pragma unroll 8
    for (int c = 0; c < 32; ++c) {
        const float f = src[(size_t)c << 10];
        const float g0 = g0p[c], g1 = g0p[CDIM + c];
        const float g2 = g0p[2 * CDIM + c], g3 = g0p[3 * CDIM + c];
        const float g = (lab == 1) ? g1 : (lab == 2) ? g2 : (lab == 3) ? g3 : g0;
        dot += f * g;
    }
    pd[w][lane] = dot;

    float ps = 0.f;
#pragma unroll 8
    for (int j = 0; j < 16; ++j)
        ps += part[(size_t)(w * 16 + j) * NPIX + n0 + lane];
    pq[w][lane] = ps;
    __syncthreads();

    if (w == 0) {
        const float den = pq[0][lane] + pq[1][lane] + pq[2][lane] + pq[3][lane]
                        - EXPDIAG;
        const float d = pd[0][lane] + pd[1][lane] + pd[2][lane] + pd[3][lane];
        float loss = 0.f;
        if (lab != 0) {
            const float num = (d - 1.0f) * (1.0f / TEMP);
            const float cnt = (float)(counts[lab] - 1);
            loss = __builtin_amdgcn_logf(den) * LN2 - num / cnt;
        }
#pragma unroll
        for (int m = 1; m < 64; m <<= 1) loss += __shfl_xor(loss, m, 64);
        if (lane == 0) {
            atomicAdd(acc, loss);
            __threadfence();
            const int old = atomicAdd(done, 1);
            if (old == 127) {
                const float tot = atomicAdd(acc, 0.0f);
                const int nv = NPIX - counts[0];
                out[0] = (nv > 0) ? tot / (float)nv : 0.0f;
            }
        }
    }
}

extern "C" void kernel_launch(void* const* d_in, const int* in_sizes, int n_in,
                              void* d_out, int out_size, void* d_ws, size_t ws_size,
                              hipStream_t stream) {
    const float* feats = (const float*)d_in[0];
    const int* labels = (const int*)d_in[1];
    float* out = (float*)d_out;
    float* W = (float*)d_ws;

    float* G      = W + OFF_G;
    int*   counts = (int*)(W + OFF_COUNTS);
    float* acc    = W + OFF_ACC;
    int*   done   = (int*)(W + OFF_DONE);
    float* part   = W + OFF_PART;
    v8bf*  swf    = (v8bf*)(W + OFF_SWF);

    k0_zero<<<3, 256, 0, stream>>>(W);
    k1_build<<<256, 256, 0, stream>>>(feats, labels, swf, G, counts);
    k3_gemm_expsum<<<32 * NCHUNK, 256, 0, stream>>>(swf, part);
    k4_loss<<<128, 256, 0, stream>>>(feats, labels, G, counts, part, acc, done, out);
}

// Round 9
// 52.752 us; speedup vs baseline: 2.0411x; 1.0500x over previous
//
#include <hip/hip_runtime.h>

#define TEMP 0.7f
#define LOG2E 1.4426950408889634f
#define LN2 0.6931471805599453f
#define NPIX 8192
#define CDIM 128
#define NCHUNK 64               // col-chunks of 128 cols
// sqrt(LOG2E / TEMP): fold exp2-conversion + temperature into bf16 operands
#define FSCALE 1.4356161f
// exp(1/TEMP) = exp(diag) since features are L2-normalized (|F|^2 == 1)
#define EXPDIAG 4.1727352f

typedef __bf16 v8bf __attribute__((ext_vector_type(8)));
typedef float f32x4 __attribute__((ext_vector_type(4)));

// workspace layout (float offsets)
#define OFF_G      0            // 4*128 floats
#define OFF_COUNTS 512          // int[4]
#define OFF_ACC    516          // 1 float
#define OFF_DONE   517          // 1 int
#define OFF_ZERON  520          // zero the first OFF_ZERON floats
#define OFF_PART   1024         // NCHUNK * 8192 floats (rowsum partials)
#define OFF_SWF    (1024 + NCHUNK * NPIX)   // NPIX*CDIM bf16

__global__ __launch_bounds__(256) void k0_zero(float* __restrict__ w) {
    const int i = blockIdx.x * 256 + threadIdx.x;
    if (i < OFF_ZERON) w[i] = 0.0f;
}

// Transpose-build: coalesced feats reads -> LDS tile (128c x 32p, pad 33),
// then emit swizzled bf16 MFMA fragments, class sums G, counts.
// 512 threads (8 waves/CU — R7's 256-thread version was 4 waves, latency-
// exposed at 1 block/CU), 256 blocks.
__global__ __launch_bounds__(512) void k1_build(
    const float* __restrict__ feats, const int* __restrict__ labels,
    v8bf* __restrict__ swf, float* __restrict__ G, int* __restrict__ counts)
{
    __shared__ float lds[128][33];
    __shared__ int lab_l[32];
    __shared__ float cs[4][4][128];

    const int t = threadIdx.x;
    const int bp = blockIdx.x >> 5;   // b' = row-block in concat order, 0..7
    const int pc = blockIdx.x & 31;   // 32-pixel chunk
    const int b = bp & 3, v = bp >> 2;
    const int bv = b * 2 + v;         // index into feats/labels batch dim
    const int p0 = pc * 32;
    const int nbase = bp * 1024 + p0;

    const float* src = feats + (size_t)bv * CDIM * 1024 + p0;
    const int px = t & 31, c16 = t >> 5;   // 16 channel-groups
#pragma unroll
    for (int i = 0; i < 8; i++) {
        const int c = i * 16 + c16;
        lds[c][px] = src[c * 1024 + px];
    }
    // labels + counts
    if (t < 32) {
        const int lab = labels[bv * 1024 + p0 + t];
        lab_l[t] = lab;
#pragma unroll
        for (int k = 0; k < 4; k++) {
            unsigned long long m = __ballot(lab == k);
            if (t == 0) atomicAdd(&counts[k], (int)__popcll(m));
        }
    }
    __syncthreads();

    // per-class partial sums: 4 quarters of 8 pixels each
    {
        const int cw = t & 127, h = t >> 7;
        float s0 = 0.f, s1 = 0.f, s2 = 0.f, s3 = 0.f;
#pragma unroll
        for (int i = 0; i < 8; i++) {
            const int nl = h * 8 + i;
            const int lab = lab_l[nl];
            const float f = lds[cw][nl];
            s0 += (lab == 0) ? f : 0.f;
            s1 += (lab == 1) ? f : 0.f;
            s2 += (lab == 2) ? f : 0.f;
            s3 += (lab == 3) ? f : 0.f;
        }
        cs[h][0][cw] = s0; cs[h][1][cw] = s1;
        cs[h][2][cw] = s2; cs[h][3][cw] = s3;
    }
    __syncthreads();
    if (t < 128) {
#pragma unroll
        for (int k = 0; k < 4; k++)
            atomicAdd(&G[k * CDIM + t],
                      cs[0][k][t] + cs[1][k][t] + cs[2][k][t] + cs[3][k][t]);
    }

    // swizzled bf16 fragment writes, single pass (512 slots = 8 frags x 64):
    // frag (ctg*4+kk), element q*16+r holds F[ctg*16+r][kk*32+q*8+j]*FSCALE
    {
        const int f = t >> 6, l = t & 63;
        const int ctl = f >> 2, kk = f & 3;
        const int q = l >> 4, r = l & 15;
        const int nl = ctl * 16 + r;
        const int c0 = kk * 32 + q * 8;
        v8bf val;
#pragma unroll
        for (int j = 0; j < 8; j++) val[j] = (__bf16)(lds[c0 + j][nl] * FSCALE);
        const int ctg = (nbase >> 4) + ctl;
        swf[(ctg * 4 + kk) * 64 + l] = val;
    }
}

// Stage one 16-col tile (4 KB, contiguous in swf) into LDS via global_load_lds.
__device__ __forceinline__ void stage_tile(const v8bf* swf, __bf16* ldsbase,
                                           int ct, int wave, int lane)
{
    const char* g = (const char*)swf + ((size_t)ct << 12) + (wave << 10) + (lane << 4);
    char* l = (char*)ldsbase + (wave << 10);
    __builtin_amdgcn_global_load_lds(
        (__attribute__((address_space(1))) void*)(char*)g,
        (__attribute__((address_space(3))) void*)l, 16, 0, 0);
}

// Fused S = F F^T (bf16 MFMA) + exp2 row-sum, SYMMETRIC without atomics:
// upper-tri 64x64 grid of 128x128 tiles (2080 blocks). Off-diag block (bi,bj)
// writes tile row-sums to part[bj][rows of bi] and tile col-sums to
// part[bi][cols of bj] — every part slot written exactly once (R3's failure
// was per-iter cross-XCD atomics; this is contention-free stores).
// B-panel (32 KB) staged once via global_load_lds; one barrier; 8 iters
// barrier-free. A-frags register-resident. Col-sums: per-lane register
// accumulate + 2 shuffles + per-wave LDS slice per iter (no runtime-indexed
// register arrays).
__global__ __launch_bounds__(256, 4) void k3_gemm_expsum(
    const v8bf* __restrict__ swf, float* __restrict__ part)
{
    __shared__ __align__(16) __bf16 bbuf[8][2048];   // 32 KB B-panel
    __shared__ float wcs[4][128];                     // per-wave colsum slices
    const int t = threadIdx.x;
    const int lane = t & 63;
    const int wave = t >> 6;

    // decode upper-triangular block (bi <= bj) over 64 strips
    int rem = blockIdx.x, bi = 0;
    while (rem >= 64 - bi) { rem -= 64 - bi; bi++; }
    const int bj = bi + rem;
    const bool offdiag = (bj != bi);

    const int rt0 = bi * 8 + wave * 2;     // wave's 32 rows = 2 row-tiles
    const int ct0 = bj * 8;                // 8 col-tiles of 16

    // stage the whole B-panel (8 x 4 KB), data never touches VGPRs
#pragma unroll
    for (int j = 0; j < 8; j++)
        stage_tile(swf, &bbuf[j][0], ct0 + j, wave, lane);

    // A fragments: 8 x v8bf = 32 VGPRs, resident
    v8bf a[2][4];
#pragma unroll
    for (int tt = 0; tt < 2; tt++)
#pragma unroll
        for (int kk = 0; kk < 4; kk++)
            a[tt][kk] = swf[((rt0 + tt) * 4 + kk) * 64 + lane];

    float rs[2][4];
#pragma unroll
    for (int tt = 0; tt < 2; tt++)
#pragma unroll
        for (int r = 0; r < 4; r++) rs[tt][r] = 0.f;

    __syncthreads();   // panel staged; no further barriers until epilogue

#pragma unroll 2
    for (int it = 0; it < 8; ++it) {
        const v8bf* bb = (const v8bf*)&bbuf[it][0];
        const v8bf b0 = bb[lane];
        const v8bf b1 = bb[64 + lane];
        const v8bf b2 = bb[128 + lane];
        const v8bf b3 = bb[192 + lane];
        float cc = 0.f;
#pragma unroll
        for (int tt = 0; tt < 2; tt++) {
            f32x4 acc = {0.f, 0.f, 0.f, 0.f};
            acc = __builtin_amdgcn_mfma_f32_16x16x32_bf16(a[tt][0], b0, acc, 0, 0, 0);
            acc = __builtin_amdgcn_mfma_f32_16x16x32_bf16(a[tt][1], b1, acc, 0, 0, 0);
            acc = __builtin_amdgcn_mfma_f32_16x16x32_bf16(a[tt][2], b2, acc, 0, 0, 0);
            acc = __builtin_amdgcn_mfma_f32_16x16x32_bf16(a[tt][3], b3, acc, 0, 0, 0);
            // acc already = S * log2(e) thanks to FSCALE folding
#pragma unroll
            for (int r = 0; r < 4; r++) {
                const float e = __builtin_amdgcn_exp2f(acc[r]);
                rs[tt][r] += e;
                cc += e;
            }
        }
        // wave's 32-row colsum for its 16 cols of tile `it`
        cc += __shfl_xor(cc, 16, 64);
        cc += __shfl_xor(cc, 32, 64);
        if (lane < 16) wcs[wave][it * 16 + lane] = cc;   // unique slot, no race
    }

    // row-sums: reduce across the 16 lanes of each C/D column group
#pragma unroll
    for (int m = 1; m < 16; m <<= 1)
#pragma unroll
        for (int tt = 0; tt < 2; tt++)
#pragma unroll
            for (int r = 0; r < 4; r++)
                rs[tt][r] += __shfl_xor(rs[tt][r], m, 64);

    if ((lane & 15) == 0) {
        const int g = lane >> 4;
        float* dst = part + (size_t)bj * NPIX + bi * 128 + wave * 32;
#pragma unroll
        for (int tt = 0; tt < 2; tt++)
#pragma unroll
            for (int r = 0; r < 4; r++)
                dst[tt * 16 + g * 4 + r] = rs[tt][r];
    }

    // col-sums: combine the 4 wave slices, store to the transposed partial
    if (offdiag) {
        __syncthreads();
        if (t < 128) {
            const float s = wcs[0][t] + wcs[1][t] + wcs[2][t] + wcs[3][t];
            part[(size_t)bi * NPIX + bj * 128 + t] = s;
        }
    }
}

// Per-anchor loss + final divide in the last block (done-counter).
// Block = 4 waves over 64 anchors (one anchor per lane). Each wave sums 16
// of the 64 rowsum partials AND dots 32 of the 128 channels; LDS combine;
// one atomicAdd per block.
__global__ __launch_bounds__(256) void k4_loss(
    const float* __restrict__ feats, const int* __restrict__ labels,
    const float* __restrict__ G, const int* __restrict__ counts,
    const float* __restrict__ part, float* __restrict__ acc,
    int* __restrict__ done, float* __restrict__ out)
{
    __shared__ float pd[4][64];
    __shared__ float pq[4][64];
    const int t = threadIdx.x, lane = t & 63, w = t >> 6;
    const int n0 = blockIdx.x * 64;
    const int bp = n0 >> 10, p0 = n0 & 1023;
    const int bv = ((bp & 3) << 1) + (bp >> 2);
    const int p = p0 + lane;
    const int lab = labels[(bv << 10) + p];

    const float* src = feats + (((size_t)bv * CDIM + w * 32) << 10) + p;
    const float* g0p = G + w * 32;
    float dot = 0.f;
#pragma unroll 8
    for (int c = 0; c < 32; ++c) {
        const float f = src[(size_t)c << 10];
        const float g0 = g0p[c], g1 = g0p[CDIM + c];
        const float g2 = g0p[2 * CDIM + c], g3 = g0p[3 * CDIM + c];
        const float g = (lab == 1) ? g1 : (lab == 2) ? g2 : (lab == 3) ? g3 : g0;
        dot += f * g;
    }
    pd[w][lane] = dot;

    float ps = 0.f;
#pragma unroll 8
    for (int j = 0; j < 16; ++j)
        ps += part[(size_t)(w * 16 + j) * NPIX + n0 + lane];
    pq[w][lane] = ps;
    __syncthreads();

    if (w == 0) {
        const float den = pq[0][lane] + pq[1][lane] + pq[2][lane] + pq[3][lane]
                        - EXPDIAG;
        const float d = pd[0][lane] + pd[1][lane] + pd[2][lane] + pd[3][lane];
        float loss = 0.f;
        if (lab != 0) {
            const float num = (d - 1.0f) * (1.0f / TEMP);
            const float cnt = (float)(counts[lab] - 1);
            loss = __builtin_amdgcn_logf(den) * LN2 - num / cnt;
        }
#pragma unroll
        for (int m = 1; m < 64; m <<= 1) loss += __shfl_xor(loss, m, 64);
        if (lane == 0) {
            atomicAdd(acc, loss);
            __threadfence();
            const int old = atomicAdd(done, 1);
            if (old == 127) {
                const float tot = atomicAdd(acc, 0.0f);
                const int nv = NPIX - counts[0];
                out[0] = (nv > 0) ? tot / (float)nv : 0.0f;
            }
        }
    }
}

extern "C" void kernel_launch(void* const* d_in, const int* in_sizes, int n_in,
                              void* d_out, int out_size, void* d_ws, size_t ws_size,
                              hipStream_t stream) {
    const float* feats = (const float*)d_in[0];
    const int* labels = (const int*)d_in[1];
    float* out = (float*)d_out;
    float* W = (float*)d_ws;

    float* G      = W + OFF_G;
    int*   counts = (int*)(W + OFF_COUNTS);
    float* acc    = W + OFF_ACC;
    int*   done   = (int*)(W + OFF_DONE);
    float* part   = W + OFF_PART;
    v8bf*  swf    = (v8bf*)(W + OFF_SWF);

    k0_zero<<<3, 256, 0, stream>>>(W);
    k1_build<<<256, 512, 0, stream>>>(feats, labels, swf, G, counts);
    k3_gemm_expsum<<<2080, 256, 0, stream>>>(swf, part);
    k4_loss<<<128, 256, 0, stream>>>(feats, labels, G, counts, part, acc, done, out);
}